// Round 6
// baseline (298.675 us; speedup 1.0000x reference)
//
#include <hip/hip_runtime.h>
#include <hip/hip_bf16.h>
#include <math.h>

#define LSEQ 128
#define BB 8
#define M_TOK (BB*LSEQ)   // 1024

// ---------------- staging: 5 weight transposes + embedding + Wfc, one launch ----------------
struct PreArgs {
    const float* src[5];
    float* dst[5];
    int OC[5], CI[5], K[5];
    const int* x;
    const float4* gen4;
    const float4* dom4;
    float4* emb4;
    const float* wf;
    const float* wc;
    float* Wfc;
};
__global__ __launch_bounds__(256) void stage_kernel(PreArgs a) {
    int y = blockIdx.y;
    if (y < 5) {
        int idx = blockIdx.x * 256 + threadIdx.x;
        int OC = a.OC[y], CI = a.CI[y], K = a.K[y];
        int total = OC * CI * K;
        if (idx >= total) return;
        int k = idx % K;
        int r = idx / K;
        int ci = r % CI;
        int oc = r / CI;
        a.dst[y][(ci * K + k) * OC + oc] = a.src[y][idx];
    } else if (y == 5) {
        int m = blockIdx.x;
        if (m >= M_TOK) return;
        int t = a.x[m];
        int i = threadIdx.x;
        if (i < 100) {
            float4 v = (i < 75) ? a.gen4[t * 75 + i] : a.dom4[t * 25 + (i - 75)];
            a.emb4[m * 100 + i] = v;
        }
    } else {
        // Wfc[r,c] = sum_n wf[r,n]*wc[n,c], r < 512 (first wave only)
        int r = blockIdx.x;
        if (r >= 512 || threadIdx.x >= 64) return;
        int l = threadIdx.x;
        float p[6] = {0,0,0,0,0,0};
        const float* row = a.wf + r * 512;
        #pragma unroll
        for (int k = 0; k < 8; ++k) {
            int n = l + 64 * k;
            float v = row[n];
            #pragma unroll
            for (int c = 0; c < 6; ++c) p[c] += v * a.wc[n * 6 + c];
        }
        #pragma unroll
        for (int c = 0; c < 6; ++c)
            for (int off = 32; off >= 1; off >>= 1) p[c] += __shfl_xor(p[c], off, 64);
        if (l == 0) {
            #pragma unroll
            for (int c = 0; c < 6; ++c) a.Wfc[r * 6 + c] = p[c];
        }
    }
}

// ---------------- conv1 (+precomp2 on y==8): 400ch -> 128(k5) ++ 128(k3), relu ----------------
__global__ __launch_bounds__(256) void conv1_v2(const float* __restrict__ emb,
        const float* __restrict__ w1T, const float* __restrict__ b1,
        const float* __restrict__ w2T, const float* __restrict__ b2,
        float* __restrict__ out,
        const float* __restrict__ wf, const float* __restrict__ bf,
        const float* __restrict__ wc, const float* __restrict__ Wfc,
        float* __restrict__ U) {
    __shared__ float xs[400 * 20];   // 32 KB
    int ot = blockIdx.y;
    if (ot == 8) {
        // precomp2: U[r, 0:12] = row_r @ [wc | Wfc], rows r = bx + 64*i
        if (threadIdx.x >= 64) return;
        int l = threadIdx.x;
        for (int i = 0; i < 9; ++i) {
            int r = blockIdx.x + 64 * i;
            if (r >= 531) break;
            const float* row = (r < 530) ? (wf + r * 512) : bf;
            float p[12];
            #pragma unroll
            for (int c = 0; c < 12; ++c) p[c] = 0.f;
            #pragma unroll
            for (int k = 0; k < 8; ++k) {
                int n = l + 64 * k;
                float v = row[n];
                #pragma unroll
                for (int c = 0; c < 6; ++c) {
                    p[c]     += v * wc[n * 6 + c];
                    p[c + 6] += v * Wfc[n * 6 + c];
                }
            }
            #pragma unroll
            for (int c = 0; c < 12; ++c)
                for (int off = 32; off >= 1; off >>= 1) p[c] += __shfl_xor(p[c], off, 64);
            if (l == 0) {
                #pragma unroll
                for (int c = 0; c < 12; ++c) U[r * 12 + c] = p[c];
            }
        }
        return;
    }
    int pt = blockIdx.x;
    int b = pt >> 3;
    int l0 = (pt & 7) << 4;
    int tid = threadIdx.x;
    for (int idx = tid; idx < 400 * 20; idx += 256) {
        int p = idx / 400;
        int ci = idx - p * 400;
        int l = l0 - 2 + p;
        float v = 0.f;
        if (l >= 0 && l < LSEQ) v = emb[(b * LSEQ + l) * 400 + ci];
        xs[ci * 20 + p] = v;
    }
    __syncthreads();
    int o = tid & 31;
    int s = tid >> 5;                // ci-slice [s*50, s*50+50)
    float acc[16];
    #pragma unroll
    for (int p = 0; p < 16; ++p) acc[p] = 0.f;
    if (ot < 4) {
        const float* wp = w1T + (s * 50 * 5) * 128 + ot * 32 + o;
        for (int i = 0; i < 50; ++i) {
            const float4* x4 = (const float4*)(xs + (s * 50 + i) * 20);
            float4 A0 = x4[0], A1 = x4[1], A2 = x4[2], A3 = x4[3], A4 = x4[4];
            float xv[20] = {A0.x,A0.y,A0.z,A0.w, A1.x,A1.y,A1.z,A1.w,
                            A2.x,A2.y,A2.z,A2.w, A3.x,A3.y,A3.z,A3.w,
                            A4.x,A4.y,A4.z,A4.w};
            #pragma unroll
            for (int k = 0; k < 5; ++k) {
                float w = wp[k * 128];
                #pragma unroll
                for (int p = 0; p < 16; ++p) acc[p] += w * xv[p + k];
            }
            wp += 640;
        }
    } else {
        const float* wp = w2T + (s * 50 * 3) * 128 + (ot - 4) * 32 + o;
        for (int i = 0; i < 50; ++i) {
            const float4* x4 = (const float4*)(xs + (s * 50 + i) * 20);
            float4 A0 = x4[0], A1 = x4[1], A2 = x4[2], A3 = x4[3], A4 = x4[4];
            float xv[20] = {A0.x,A0.y,A0.z,A0.w, A1.x,A1.y,A1.z,A1.w,
                            A2.x,A2.y,A2.z,A2.w, A3.x,A3.y,A3.z,A3.w,
                            A4.x,A4.y,A4.z,A4.w};
            #pragma unroll
            for (int k = 0; k < 3; ++k) {
                float w = wp[k * 128];
                #pragma unroll
                for (int p = 0; p < 16; ++p) acc[p] += w * xv[p + k + 1];
            }
            wp += 384;
        }
    }
    __syncthreads();
    float* rs = xs;
    #pragma unroll
    for (int p = 0; p < 16; ++p) rs[s * 512 + p * 32 + o] = acc[p];
    __syncthreads();
    #pragma unroll
    for (int r = 0; r < 2; ++r) {
        int idx = r * 256 + tid;
        int p = idx >> 5, oo = idx & 31;
        float sum = 0.f;
        #pragma unroll
        for (int ss = 0; ss < 8; ++ss) sum += rs[ss * 512 + p * 32 + oo];
        float bs = (ot < 4) ? b1[ot * 32 + oo] : b2[(ot - 4) * 32 + oo];
        out[(b * LSEQ + l0 + p) * 256 + ot * 32 + oo] = fmaxf(sum + bs, 0.f);
    }
}

// ---------------- conv256: 256->256, k=5, p=2, relu ----------------
__global__ __launch_bounds__(256) void conv256_v2(const float* __restrict__ in,
        const float* __restrict__ wT, const float* __restrict__ bias,
        float* __restrict__ out) {
    __shared__ float xs[256 * 20];
    int pt = blockIdx.x;
    int b = pt >> 3;
    int l0 = (pt & 7) << 4;
    int ot = blockIdx.y;
    int tid = threadIdx.x;
    for (int idx = tid; idx < 256 * 20; idx += 256) {
        int p = idx >> 8;
        int ci = idx & 255;
        int l = l0 - 2 + p;
        float v = 0.f;
        if (l >= 0 && l < LSEQ) v = in[(b * LSEQ + l) * 256 + ci];
        xs[ci * 20 + p] = v;
    }
    __syncthreads();
    int o = tid & 31;
    int s = tid >> 5;
    int oc0 = ot * 32;
    float acc[16];
    #pragma unroll
    for (int p = 0; p < 16; ++p) acc[p] = 0.f;
    const float* wp = wT + (s * 32 * 5) * 256 + oc0 + o;
    for (int i = 0; i < 32; ++i) {
        const float4* x4 = (const float4*)(xs + (s * 32 + i) * 20);
        float4 A0 = x4[0], A1 = x4[1], A2 = x4[2], A3 = x4[3], A4 = x4[4];
        float xv[20] = {A0.x,A0.y,A0.z,A0.w, A1.x,A1.y,A1.z,A1.w,
                        A2.x,A2.y,A2.z,A2.w, A3.x,A3.y,A3.z,A3.w,
                        A4.x,A4.y,A4.z,A4.w};
        #pragma unroll
        for (int k = 0; k < 5; ++k) {
            float w = wp[k * 256];
            #pragma unroll
            for (int p = 0; p < 16; ++p) acc[p] += w * xv[p + k];
        }
        wp += 1280;
    }
    __syncthreads();
    float* rs = xs;
    #pragma unroll
    for (int p = 0; p < 16; ++p) rs[s * 512 + p * 32 + o] = acc[p];
    __syncthreads();
    #pragma unroll
    for (int r = 0; r < 2; ++r) {
        int idx = r * 256 + tid;
        int p = idx >> 5, oo = idx & 31;
        float sum = 0.f;
        #pragma unroll
        for (int ss = 0; ss < 8; ++ss) sum += rs[ss * 512 + p * 32 + oo];
        out[(b * LSEQ + l0 + p) * 256 + oc0 + oo] = fmaxf(sum + bias[oc0 + oo], 0.f);
    }
}

// ---------------- q/v projection: 2 waves per block (wave0=q, wave1=v) ----------------
__global__ __launch_bounds__(128) void qv_v2(const float* __restrict__ xc,
        const float* __restrict__ wq, const float* __restrict__ bq,
        const float* __restrict__ wv, const float* __restrict__ bv,
        float* __restrict__ q, float* __restrict__ v) {
    int m = blockIdx.x;
    int tid = threadIdx.x;
    int w = tid >> 6, d = tid & 63;
    if (d >= 50) return;
    const float* W = w ? wv : wq;
    float a = w ? bv[d] : bq[d];
    const float* xm = xc + m * 256;
    #pragma unroll 8
    for (int c = 0; c < 256; ++c) a += xm[c] * W[c * 50 + d];
    (w ? v : q)[m * 50 + d] = a;
}

// ---------------- attention v2: 256 threads/row, LDS-staged V, fast tanh ----------------
__global__ __launch_bounds__(256) void attn_v2(const float* __restrict__ xc,
        const float* __restrict__ q, const float* __restrict__ v,
        const float* __restrict__ vv, const float* __restrict__ xmask,
        const float* __restrict__ wc, const float* __restrict__ bc,
        float* __restrict__ xc2, float* __restrict__ f0, float* __restrict__ g0) {
    __shared__ float vs[128 * 50];   // 25.6 KB
    __shared__ float spart[128], aarr[128], xrow[256], qrow[52], vvs[52], red[4];
    int bi = blockIdx.x;             // b*L + i
    int b = bi >> 7;
    int tid = threadIdx.x;
    for (int idx = tid; idx < 128 * 50; idx += 256) vs[idx] = v[b * 6400 + idx];
    if (tid < 50) { qrow[tid] = q[bi * 50 + tid]; vvs[tid] = vv[tid]; }
    __syncthreads();
    int j = tid & 127, half = tid >> 7;
    int d0 = half * 25;
    const float* vj = vs + j * 50 + d0;
    float s = 0.f;
    #pragma unroll
    for (int d = 0; d < 25; ++d) {
        float x = qrow[d0 + d] + vj[d];
        float e = __expf(2.f * x);               // tanh(x) = 1 - 2/(e^(2x)+1)
        s += (1.f - 2.f / (e + 1.f)) * vvs[d0 + d];
    }
    if (half) spart[j] = s;
    __syncthreads();
    float stot = 0.f;
    if (!half) {
        stot = s + spart[j];
        if (xmask[b * LSEQ + j] == 0.f) stot = -1e9f;
    }
    if (tid < 128) {
        float m = stot;
        #pragma unroll
        for (int off = 32; off >= 1; off >>= 1) m = fmaxf(m, __shfl_xor(m, off, 64));
        if ((tid & 63) == 0) red[tid >> 6] = m;
    }
    __syncthreads();
    float mx = fmaxf(red[0], red[1]);
    float e = 0.f;
    if (tid < 128) {
        e = __expf(stot - mx);
        float su = e;
        #pragma unroll
        for (int off = 32; off >= 1; off >>= 1) su += __shfl_xor(su, off, 64);
        if ((tid & 63) == 0) red[2 + (tid >> 6)] = su;
    }
    __syncthreads();
    float denom = red[2] + red[3];
    if (tid < 128) aarr[j] = e / denom;
    __syncthreads();
    float maskI = xmask[bi];
    const float* xcb = xc + b * LSEQ * 256;
    float acc = 0.f;
    #pragma unroll 8
    for (int jj = 0; jj < 128; ++jj) acc += aarr[jj] * xcb[jj * 256 + tid];
    float val = xc[bi * 256 + tid] + acc * maskI;
    xc2[bi * 256 + tid] = val;
    xrow[tid] = val;
    __syncthreads();
    int grp = tid >> 4, l16 = tid & 15;
    if (grp < 12) {
        int c = grp % 6, gsel = grp / 6;
        const float* wcc = wc + gsel * 256 * 6 + c;
        float a = 0.f;
        #pragma unroll
        for (int ch = l16; ch < 256; ch += 16) a += xrow[ch] * wcc[ch * 6];
        #pragma unroll
        for (int off = 8; off >= 1; off >>= 1) a += __shfl_down(a, off, 16);
        if (l16 == 0) {
            if (gsel == 0) f0[bi * 6 + c] = a + bc[c];
            else           g0[bi * 6 + c] = a;
        }
    }
}

// ---------------- fused hop tail: lm0 + hopfold + lm1 + f2/g2, one block per batch ----------------
// wave-scan helper: inclusive prefix-max over 128 elems, 2 per lane
__global__ __launch_bounds__(1024) void tail_kernel(const float* __restrict__ xc2,
        const float* __restrict__ U, const float* __restrict__ f0g,
        const float* __restrict__ g0g, const float* __restrict__ bc,
        float* __restrict__ f2, float* __restrict__ g2) {
    __shared__ float Ul[531 * 12];   // 25.5 KB
    __shared__ float sf[768], sg[768];      // f0,g0 channel-major [c*128+p]
    __shared__ float pmax[768], smax[768];  // scans
    __shared__ float lm[768];               // [p*6+c]
    __shared__ float fF[128 * 12], fG[128 * 12];  // f1|phi1, g1|gam1 [t*12+c]
    int b = blockIdx.x;
    int tid = threadIdx.x;
    int w = tid >> 6, l = tid & 63;
    for (int i = tid; i < 531 * 12; i += 1024) Ul[i] = U[i];
    for (int i = tid; i < 768; i += 1024) {
        int p = i / 6, c = i - p * 6;
        sf[c * 128 + p] = f0g[b * 768 + i];
        sg[c * 128 + p] = g0g[b * 768 + i];
    }
    __syncthreads();
    // ---- phase A: lm0 scans (waves 0..5: prefix-f; 6..11: suffix-g) ----
    if (w < 6) {
        int c = w;
        float v0 = sf[c * 128 + 2 * l], v1 = sf[c * 128 + 2 * l + 1];
        float lo = fmaxf(v0, v1), sc = lo;
        #pragma unroll
        for (int off = 1; off < 64; off <<= 1) {
            float o = __shfl_up(sc, off, 64);
            if (l >= off) sc = fmaxf(sc, o);
        }
        float E = __shfl_up(sc, 1, 64); if (l == 0) E = -INFINITY;
        pmax[c * 128 + 2 * l] = fmaxf(E, v0);
        pmax[c * 128 + 2 * l + 1] = sc;
    } else if (w < 12) {
        int c = w - 6;
        int i0 = 127 - 2 * l, i1 = 126 - 2 * l;
        float v0 = sg[c * 128 + i0], v1 = sg[c * 128 + i1];
        float lo = fmaxf(v0, v1), sc = lo;
        #pragma unroll
        for (int off = 1; off < 64; off <<= 1) {
            float o = __shfl_up(sc, off, 64);
            if (l >= off) sc = fmaxf(sc, o);
        }
        float E = __shfl_up(sc, 1, 64); if (l == 0) E = -INFINITY;
        smax[c * 128 + i0] = fmaxf(E, v0);
        smax[c * 128 + i1] = sc;
    }
    __syncthreads();
    if (tid < 768) {
        int p = tid / 6, c = tid - p * 6;
        float M1 = pmax[c * 128 + p] + sg[c * 128 + p];
        if (p < LSEQ - 1) M1 = fmaxf(M1, 0.f);
        float M2 = sf[c * 128 + p] + smax[c * 128 + p];
        if (p > 0) M2 = fmaxf(M2, 0.f);
        lm[p * 6 + c] = fmaxf(M1, M2);
    }
    __syncthreads();
    // ---- phase B: hopfold. t=tid>>3, y=(tid>>2)&1, ks=tid&3 ----
    {
        int t = tid >> 3, y = (tid >> 2) & 1, ks = tid & 3;
        int ybase = y ? 256 : 0;
        float acc[12];
        #pragma unroll
        for (int c = 0; c < 12; ++c) acc[c] = 0.f;
        const float4* xr = (const float4*)(xc2 + (b * LSEQ + t) * 256 + ks * 64);
        #pragma unroll 4
        for (int kk = 0; kk < 16; ++kk) {
            float4 x4 = xr[kk];
            int kb = (ybase + ks * 64 + kk * 4) * 12;
            #pragma unroll
            for (int c = 0; c < 12; ++c) {
                acc[c] += x4.x * Ul[kb + c] + x4.y * Ul[kb + 12 + c]
                        + x4.z * Ul[kb + 24 + c] + x4.w * Ul[kb + 36 + c];
            }
        }
        #pragma unroll
        for (int c = 0; c < 12; ++c) {
            acc[c] += __shfl_down(acc[c], 1, 4);
            acc[c] += __shfl_down(acc[c], 2, 4);
        }
        if (ks == 0) {
            int Bb = (y ? 518 : 512) * 12;
            int Db = 524 * 12;
            float lmv[6], fgv[6];
            #pragma unroll
            for (int j2 = 0; j2 < 6; ++j2) {
                lmv[j2] = lm[t * 6 + j2];
                fgv[j2] = y ? sg[j2 * 128 + t] : sf[j2 * 128 + t];
            }
            float* dst = y ? (fG + t * 12) : (fF + t * 12);
            #pragma unroll
            for (int c = 0; c < 12; ++c) {
                float s = acc[c];
                #pragma unroll
                for (int j2 = 0; j2 < 6; ++j2)
                    s += lmv[j2] * Ul[Bb + j2 * 12 + c] + fgv[j2] * Ul[Db + j2 * 12 + c];
                if (!y) { s += Ul[530 * 12 + c]; if (c < 6) s += bc[c]; }
                dst[c] = s;
            }
        }
    }
    __syncthreads();
    // ---- phase C: lm1 scans on f1 (fF[:,0:6]) and g1 (fG[:,0:6]) ----
    if (w < 6) {
        int c = w;
        float v0 = fF[(2 * l) * 12 + c], v1 = fF[(2 * l + 1) * 12 + c];
        float lo = fmaxf(v0, v1), sc = lo;
        #pragma unroll
        for (int off = 1; off < 64; off <<= 1) {
            float o = __shfl_up(sc, off, 64);
            if (l >= off) sc = fmaxf(sc, o);
        }
        float E = __shfl_up(sc, 1, 64); if (l == 0) E = -INFINITY;
        pmax[c * 128 + 2 * l] = fmaxf(E, v0);
        pmax[c * 128 + 2 * l + 1] = sc;
    } else if (w < 12) {
        int c = w - 6;
        int i0 = 127 - 2 * l, i1 = 126 - 2 * l;
        float v0 = fG[i0 * 12 + c], v1 = fG[i1 * 12 + c];
        float lo = fmaxf(v0, v1), sc = lo;
        #pragma unroll
        for (int off = 1; off < 64; off <<= 1) {
            float o = __shfl_up(sc, off, 64);
            if (l >= off) sc = fmaxf(sc, o);
        }
        float E = __shfl_up(sc, 1, 64); if (l == 0) E = -INFINITY;
        smax[c * 128 + i0] = fmaxf(E, v0);
        smax[c * 128 + i1] = sc;
    }
    __syncthreads();
    if (tid < 768) {
        int p = tid / 6, c = tid - p * 6;
        float M1 = pmax[c * 128 + p] + fG[p * 12 + c];
        if (p < LSEQ - 1) M1 = fmaxf(M1, 0.f);
        float M2 = fF[p * 12 + c] + smax[c * 128 + p];
        if (p > 0) M2 = fmaxf(M2, 0.f);
        lm[p * 6 + c] = fmaxf(M1, M2);
    }
    __syncthreads();
    // ---- phase D: f2/g2 ----
    if (tid < 768) {
        int p = tid / 6, c = tid - p * 6;
        float lmv[6], f1v[6], g1v[6];
        #pragma unroll
        for (int j2 = 0; j2 < 6; ++j2) {
            lmv[j2] = lm[p * 6 + j2];
            f1v[j2] = fF[p * 12 + j2];
            g1v[j2] = fG[p * 12 + j2];
        }
        float sfv = fF[p * 12 + 6 + c] + Ul[530 * 12 + c] + bc[c];
        float sgv = fG[p * 12 + 6 + c];
        #pragma unroll
        for (int j2 = 0; j2 < 6; ++j2) {
            sfv += lmv[j2] * Ul[(512 + j2) * 12 + c] + f1v[j2] * Ul[(524 + j2) * 12 + c];
            sgv += lmv[j2] * Ul[(518 + j2) * 12 + c] + g1v[j2] * Ul[(524 + j2) * 12 + c];
        }
        f2[b * 768 + tid] = sfv;
        g2[b * 768 + tid] = sgv;
    }
}

// ---------------- final separable write ----------------
__global__ __launch_bounds__(256) void writeout_kernel(const float* __restrict__ f2,
        const float* __restrict__ g2, float* __restrict__ out) {
    int idx = blockIdx.x * 256 + threadIdx.x;   // < 8*128*128*6
    int c = idx % 6;
    int r = idx / 6;
    int j = r & 127;
    int bi = r >> 7;
    int b = bi >> 7;
    out[idx] = f2[bi * 6 + c] + g2[(b * LSEQ + j) * 6 + c];
}

extern "C" void kernel_launch(void* const* d_in, const int* in_sizes, int n_in,
                              void* d_out, int out_size, void* d_ws, size_t ws_size,
                              hipStream_t stream) {
    const int*   x     = (const int*)d_in[0];
    const float* xmask = (const float*)d_in[2];
    const float* gen   = (const float*)d_in[3];
    const float* dom   = (const float*)d_in[4];
    const float* w1    = (const float*)d_in[5];
    const float* b1    = (const float*)d_in[6];
    const float* w2    = (const float*)d_in[7];
    const float* b2    = (const float*)d_in[8];
    const float* w3    = (const float*)d_in[9];
    const float* b3    = (const float*)d_in[10];
    const float* w4    = (const float*)d_in[11];
    const float* b4    = (const float*)d_in[12];
    const float* w5    = (const float*)d_in[13];
    const float* b5    = (const float*)d_in[14];
    const float* wq    = (const float*)d_in[15];
    const float* bq    = (const float*)d_in[16];
    const float* wv    = (const float*)d_in[17];
    const float* bv    = (const float*)d_in[18];
    const float* vv    = (const float*)d_in[19];
    const float* wf    = (const float*)d_in[20];
    const float* bf    = (const float*)d_in[21];
    const float* wc    = (const float*)d_in[22];
    const float* bc    = (const float*)d_in[23];

    float* ws = (float*)d_ws;
    float* emb   = ws;                  // 409600
    float* bufA  = emb   + 409600;      // 262144
    float* bufB  = bufA  + 262144;      // 262144
    float* xc2   = bufB  + 262144;      // 262144
    float* qb    = xc2   + 262144;      // 51200
    float* vb    = qb    + 51200;       // 51200
    float* w1T   = vb    + 51200;       // 256000
    float* w2T   = w1T   + 256000;      // 153600
    float* w3T   = w2T   + 153600;      // 327680
    float* w4T   = w3T   + 327680;      // 327680
    float* w5T   = w4T   + 327680;      // 327680
    float* Wfc   = w5T   + 327680;      // 3072
    float* U     = Wfc   + 3072;        // 6372
    float* f0    = U     + 6372;        // 6144
    float* g0    = f0    + 6144;
    float* f2    = g0    + 6144;
    float* g2    = f2    + 6144;

    // --- staging: transposes + embedding + Wfc, one launch ---
    PreArgs pa;
    pa.src[0] = w1;  pa.dst[0] = w1T; pa.OC[0] = 128; pa.CI[0] = 400; pa.K[0] = 5;
    pa.src[1] = w2;  pa.dst[1] = w2T; pa.OC[1] = 128; pa.CI[1] = 400; pa.K[1] = 3;
    pa.src[2] = w3;  pa.dst[2] = w3T; pa.OC[2] = 256; pa.CI[2] = 256; pa.K[2] = 5;
    pa.src[3] = w4;  pa.dst[3] = w4T; pa.OC[3] = 256; pa.CI[3] = 256; pa.K[3] = 5;
    pa.src[4] = w5;  pa.dst[4] = w5T; pa.OC[4] = 256; pa.CI[4] = 256; pa.K[4] = 5;
    pa.x = x; pa.gen4 = (const float4*)gen; pa.dom4 = (const float4*)dom;
    pa.emb4 = (float4*)emb;
    pa.wf = wf; pa.wc = wc; pa.Wfc = Wfc;
    stage_kernel<<<dim3(1280, 7), 256, 0, stream>>>(pa);

    // --- conv1 (+U precompute on y==8) ---
    conv1_v2<<<dim3(64, 9), 256, 0, stream>>>(emb, w1T, b1, w2T, b2, bufA,
                                              wf, bf, wc, Wfc, U);
    conv256_v2<<<dim3(64, 8), 256, 0, stream>>>(bufA, w3T, b3, bufB);
    conv256_v2<<<dim3(64, 8), 256, 0, stream>>>(bufB, w4T, b4, bufA);
    conv256_v2<<<dim3(64, 8), 256, 0, stream>>>(bufA, w5T, b5, bufB);
    // xc = bufB

    // --- attention (+ fused f0/g0) ---
    qv_v2<<<M_TOK, 128, 0, stream>>>(bufB, wq, bq, wv, bv, qb, vb);
    attn_v2<<<M_TOK, 256, 0, stream>>>(bufB, qb, vb, vv, xmask, wc, bc, xc2, f0, g0);

    // --- fused hop tail ---
    tail_kernel<<<BB, 1024, 0, stream>>>(xc2, U, f0, g0, bc, f2, g2);

    // --- out[b,i,j,c] = f2[b,i,c] + g2[b,j,c] ---
    writeout_kernel<<<(BB*LSEQ*LSEQ*6)/256, 256, 0, stream>>>(f2, g2, (float*)d_out);
}

// Round 7
// 261.817 us; speedup vs baseline: 1.1408x; 1.1408x over previous
//
#include <hip/hip_runtime.h>
#include <hip/hip_bf16.h>
#include <math.h>

#define LSEQ 128
#define BB 8
#define M_TOK (BB*LSEQ)   // 1024

// ---------------- staging: 5 weight transposes + embedding + Wfc, one launch ----------------
struct PreArgs {
    const float* src[5];
    float* dst[5];
    int OC[5], CI[5], K[5];
    const int* x;
    const float4* gen4;
    const float4* dom4;
    float4* emb4;
    const float* wf;
    const float* wc;
    float* Wfc;
};
__global__ __launch_bounds__(256) void stage_kernel(PreArgs a) {
    int y = blockIdx.y;
    if (y < 5) {
        int idx = blockIdx.x * 256 + threadIdx.x;
        int OC = a.OC[y], CI = a.CI[y], K = a.K[y];
        int total = OC * CI * K;
        if (idx >= total) return;
        int k = idx % K;
        int r = idx / K;
        int ci = r % CI;
        int oc = r / CI;
        a.dst[y][(ci * K + k) * OC + oc] = a.src[y][idx];
    } else if (y == 5) {
        int m = blockIdx.x;
        if (m >= M_TOK) return;
        int t = a.x[m];
        int i = threadIdx.x;
        if (i < 100) {
            float4 v = (i < 75) ? a.gen4[t * 75 + i] : a.dom4[t * 25 + (i - 75)];
            a.emb4[m * 100 + i] = v;
        }
    } else {
        // Wfc[r,c] = sum_n wf[r,n]*wc[n,c], r < 512 (first wave only)
        int r = blockIdx.x;
        if (r >= 512 || threadIdx.x >= 64) return;
        int l = threadIdx.x;
        float p[6] = {0,0,0,0,0,0};
        const float* row = a.wf + r * 512;
        #pragma unroll
        for (int k = 0; k < 8; ++k) {
            int n = l + 64 * k;
            float v = row[n];
            #pragma unroll
            for (int c = 0; c < 6; ++c) p[c] += v * a.wc[n * 6 + c];
        }
        #pragma unroll
        for (int c = 0; c < 6; ++c)
            for (int off = 32; off >= 1; off >>= 1) p[c] += __shfl_xor(p[c], off, 64);
        if (l == 0) {
            #pragma unroll
            for (int c = 0; c < 6; ++c) a.Wfc[r * 6 + c] = p[c];
        }
    }
}

// ---------------- conv1 (+precomp2 on y==8): 400ch -> 128(k5) ++ 128(k3), relu ----------------
__global__ __launch_bounds__(256) void conv1_v2(const float* __restrict__ emb,
        const float* __restrict__ w1T, const float* __restrict__ b1,
        const float* __restrict__ w2T, const float* __restrict__ b2,
        float* __restrict__ out,
        const float* __restrict__ wf, const float* __restrict__ bf,
        const float* __restrict__ wc, const float* __restrict__ Wfc,
        float* __restrict__ U) {
    __shared__ float xs[400 * 20];   // 32 KB
    int ot = blockIdx.y;
    if (ot == 8) {
        // precomp2: U[r, 0:12] = row_r @ [wc | Wfc], rows r = bx + 64*i
        if (threadIdx.x >= 64) return;
        int l = threadIdx.x;
        for (int i = 0; i < 9; ++i) {
            int r = blockIdx.x + 64 * i;
            if (r >= 531) break;
            const float* row = (r < 530) ? (wf + r * 512) : bf;
            float p[12];
            #pragma unroll
            for (int c = 0; c < 12; ++c) p[c] = 0.f;
            #pragma unroll
            for (int k = 0; k < 8; ++k) {
                int n = l + 64 * k;
                float v = row[n];
                #pragma unroll
                for (int c = 0; c < 6; ++c) {
                    p[c]     += v * wc[n * 6 + c];
                    p[c + 6] += v * Wfc[n * 6 + c];
                }
            }
            #pragma unroll
            for (int c = 0; c < 12; ++c)
                for (int off = 32; off >= 1; off >>= 1) p[c] += __shfl_xor(p[c], off, 64);
            if (l == 0) {
                #pragma unroll
                for (int c = 0; c < 12; ++c) U[r * 12 + c] = p[c];
            }
        }
        return;
    }
    int pt = blockIdx.x;
    int b = pt >> 3;
    int l0 = (pt & 7) << 4;
    int tid = threadIdx.x;
    for (int idx = tid; idx < 400 * 20; idx += 256) {
        int p = idx / 400;
        int ci = idx - p * 400;
        int l = l0 - 2 + p;
        float v = 0.f;
        if (l >= 0 && l < LSEQ) v = emb[(b * LSEQ + l) * 400 + ci];
        xs[ci * 20 + p] = v;
    }
    __syncthreads();
    int o = tid & 31;
    int s = tid >> 5;                // ci-slice [s*50, s*50+50)
    float acc[16];
    #pragma unroll
    for (int p = 0; p < 16; ++p) acc[p] = 0.f;
    if (ot < 4) {
        const float* wp = w1T + (s * 50 * 5) * 128 + ot * 32 + o;
        for (int i = 0; i < 50; ++i) {
            const float4* x4 = (const float4*)(xs + (s * 50 + i) * 20);
            float4 A0 = x4[0], A1 = x4[1], A2 = x4[2], A3 = x4[3], A4 = x4[4];
            float xv[20] = {A0.x,A0.y,A0.z,A0.w, A1.x,A1.y,A1.z,A1.w,
                            A2.x,A2.y,A2.z,A2.w, A3.x,A3.y,A3.z,A3.w,
                            A4.x,A4.y,A4.z,A4.w};
            #pragma unroll
            for (int k = 0; k < 5; ++k) {
                float w = wp[k * 128];
                #pragma unroll
                for (int p = 0; p < 16; ++p) acc[p] += w * xv[p + k];
            }
            wp += 640;
        }
    } else {
        const float* wp = w2T + (s * 50 * 3) * 128 + (ot - 4) * 32 + o;
        for (int i = 0; i < 50; ++i) {
            const float4* x4 = (const float4*)(xs + (s * 50 + i) * 20);
            float4 A0 = x4[0], A1 = x4[1], A2 = x4[2], A3 = x4[3], A4 = x4[4];
            float xv[20] = {A0.x,A0.y,A0.z,A0.w, A1.x,A1.y,A1.z,A1.w,
                            A2.x,A2.y,A2.z,A2.w, A3.x,A3.y,A3.z,A3.w,
                            A4.x,A4.y,A4.z,A4.w};
            #pragma unroll
            for (int k = 0; k < 3; ++k) {
                float w = wp[k * 128];
                #pragma unroll
                for (int p = 0; p < 16; ++p) acc[p] += w * xv[p + k + 1];
            }
            wp += 384;
        }
    }
    __syncthreads();
    float* rs = xs;
    #pragma unroll
    for (int p = 0; p < 16; ++p) rs[s * 512 + p * 32 + o] = acc[p];
    __syncthreads();
    #pragma unroll
    for (int r = 0; r < 2; ++r) {
        int idx = r * 256 + tid;
        int p = idx >> 5, oo = idx & 31;
        float sum = 0.f;
        #pragma unroll
        for (int ss = 0; ss < 8; ++ss) sum += rs[ss * 512 + p * 32 + oo];
        float bs = (ot < 4) ? b1[ot * 32 + oo] : b2[(ot - 4) * 32 + oo];
        out[(b * LSEQ + l0 + p) * 256 + ot * 32 + oo] = fmaxf(sum + bs, 0.f);
    }
}

// ---------------- conv256: 256->256, k=5, p=2, relu ----------------
__global__ __launch_bounds__(256) void conv256_v2(const float* __restrict__ in,
        const float* __restrict__ wT, const float* __restrict__ bias,
        float* __restrict__ out) {
    __shared__ float xs[256 * 20];
    int pt = blockIdx.x;
    int b = pt >> 3;
    int l0 = (pt & 7) << 4;
    int ot = blockIdx.y;
    int tid = threadIdx.x;
    for (int idx = tid; idx < 256 * 20; idx += 256) {
        int p = idx >> 8;
        int ci = idx & 255;
        int l = l0 - 2 + p;
        float v = 0.f;
        if (l >= 0 && l < LSEQ) v = in[(b * LSEQ + l) * 256 + ci];
        xs[ci * 20 + p] = v;
    }
    __syncthreads();
    int o = tid & 31;
    int s = tid >> 5;
    int oc0 = ot * 32;
    float acc[16];
    #pragma unroll
    for (int p = 0; p < 16; ++p) acc[p] = 0.f;
    const float* wp = wT + (s * 32 * 5) * 256 + oc0 + o;
    for (int i = 0; i < 32; ++i) {
        const float4* x4 = (const float4*)(xs + (s * 32 + i) * 20);
        float4 A0 = x4[0], A1 = x4[1], A2 = x4[2], A3 = x4[3], A4 = x4[4];
        float xv[20] = {A0.x,A0.y,A0.z,A0.w, A1.x,A1.y,A1.z,A1.w,
                        A2.x,A2.y,A2.z,A2.w, A3.x,A3.y,A3.z,A3.w,
                        A4.x,A4.y,A4.z,A4.w};
        #pragma unroll
        for (int k = 0; k < 5; ++k) {
            float w = wp[k * 256];
            #pragma unroll
            for (int p = 0; p < 16; ++p) acc[p] += w * xv[p + k];
        }
        wp += 1280;
    }
    __syncthreads();
    float* rs = xs;
    #pragma unroll
    for (int p = 0; p < 16; ++p) rs[s * 512 + p * 32 + o] = acc[p];
    __syncthreads();
    #pragma unroll
    for (int r = 0; r < 2; ++r) {
        int idx = r * 256 + tid;
        int p = idx >> 5, oo = idx & 31;
        float sum = 0.f;
        #pragma unroll
        for (int ss = 0; ss < 8; ++ss) sum += rs[ss * 512 + p * 32 + oo];
        out[(b * LSEQ + l0 + p) * 256 + oc0 + oo] = fmaxf(sum + bias[oc0 + oo], 0.f);
    }
}

// ---------------- q/v projection: 2 waves per block (wave0=q, wave1=v) ----------------
__global__ __launch_bounds__(128) void qv_v2(const float* __restrict__ xc,
        const float* __restrict__ wq, const float* __restrict__ bq,
        const float* __restrict__ wv, const float* __restrict__ bv,
        float* __restrict__ q, float* __restrict__ v) {
    int m = blockIdx.x;
    int tid = threadIdx.x;
    int w = tid >> 6, d = tid & 63;
    if (d >= 50) return;
    const float* W = w ? wv : wq;
    float a = w ? bv[d] : bq[d];
    const float* xm = xc + m * 256;
    #pragma unroll 8
    for (int c = 0; c < 256; ++c) a += xm[c] * W[c * 50 + d];
    (w ? v : q)[m * 50 + d] = a;
}

// ---------------- attention v2: 256 threads/row, LDS-staged V, fast tanh ----------------
__global__ __launch_bounds__(256) void attn_v2(const float* __restrict__ xc,
        const float* __restrict__ q, const float* __restrict__ v,
        const float* __restrict__ vv, const float* __restrict__ xmask,
        const float* __restrict__ wc, const float* __restrict__ bc,
        float* __restrict__ xc2, float* __restrict__ f0, float* __restrict__ g0) {
    __shared__ float vs[128 * 50];   // 25.6 KB
    __shared__ float spart[128], aarr[128], xrow[256], qrow[52], vvs[52], red[4];
    int bi = blockIdx.x;             // b*L + i
    int b = bi >> 7;
    int tid = threadIdx.x;
    for (int idx = tid; idx < 128 * 50; idx += 256) vs[idx] = v[b * 6400 + idx];
    if (tid < 50) { qrow[tid] = q[bi * 50 + tid]; vvs[tid] = vv[tid]; }
    __syncthreads();
    int j = tid & 127, half = tid >> 7;
    int d0 = half * 25;
    const float* vj = vs + j * 50 + d0;
    float s = 0.f;
    #pragma unroll
    for (int d = 0; d < 25; ++d) {
        float x = qrow[d0 + d] + vj[d];
        float e = __expf(2.f * x);               // tanh(x) = 1 - 2/(e^(2x)+1)
        s += (1.f - 2.f / (e + 1.f)) * vvs[d0 + d];
    }
    if (half) spart[j] = s;
    __syncthreads();
    float stot = 0.f;
    if (!half) {
        stot = s + spart[j];
        if (xmask[b * LSEQ + j] == 0.f) stot = -1e9f;
    }
    if (tid < 128) {
        float m = stot;
        #pragma unroll
        for (int off = 32; off >= 1; off >>= 1) m = fmaxf(m, __shfl_xor(m, off, 64));
        if ((tid & 63) == 0) red[tid >> 6] = m;
    }
    __syncthreads();
    float mx = fmaxf(red[0], red[1]);
    float e = 0.f;
    if (tid < 128) {
        e = __expf(stot - mx);
        float su = e;
        #pragma unroll
        for (int off = 32; off >= 1; off >>= 1) su += __shfl_xor(su, off, 64);
        if ((tid & 63) == 0) red[2 + (tid >> 6)] = su;
    }
    __syncthreads();
    float denom = red[2] + red[3];
    if (tid < 128) aarr[j] = e / denom;
    __syncthreads();
    float maskI = xmask[bi];
    const float* xcb = xc + b * LSEQ * 256;
    float acc = 0.f;
    #pragma unroll 8
    for (int jj = 0; jj < 128; ++jj) acc += aarr[jj] * xcb[jj * 256 + tid];
    float val = xc[bi * 256 + tid] + acc * maskI;
    xc2[bi * 256 + tid] = val;
    xrow[tid] = val;
    __syncthreads();
    int grp = tid >> 4, l16 = tid & 15;
    if (grp < 12) {
        int c = grp % 6, gsel = grp / 6;
        const float* wcc = wc + gsel * 256 * 6 + c;
        float a = 0.f;
        #pragma unroll
        for (int ch = l16; ch < 256; ch += 16) a += xrow[ch] * wcc[ch * 6];
        #pragma unroll
        for (int off = 8; off >= 1; off >>= 1) a += __shfl_down(a, off, 16);
        if (l16 == 0) {
            if (gsel == 0) f0[bi * 6 + c] = a + bc[c];
            else           g0[bi * 6 + c] = a;
        }
    }
}

// ---------------- lm scan (strided input): parallel prefix/suffix max ----------------
__global__ __launch_bounds__(128) void lm_scan_v3(const float* __restrict__ f,
        const float* __restrict__ g, int stride, float* __restrict__ lm) {
    __shared__ float sf[128], sg[128];
    int bc = blockIdx.x;          // b*6 + c
    int b = bc / 6, c = bc - b * 6;
    int p = threadIdx.x;
    float fv = f[(b * LSEQ + p) * stride + c];
    float gv = g[(b * LSEQ + p) * stride + c];
    sf[p] = fv; sg[p] = gv;
    __syncthreads();
    float pf = fv, sgx = gv;
    #pragma unroll
    for (int off = 1; off < 128; off <<= 1) {
        float a = (p >= off) ? sf[p - off] : -INFINITY;
        float d = (p + off < 128) ? sg[p + off] : -INFINITY;
        __syncthreads();
        pf = fmaxf(pf, a); sgx = fmaxf(sgx, d);
        sf[p] = pf; sg[p] = sgx;
        __syncthreads();
    }
    float M1 = pf + gv;
    if (p < LSEQ - 1) M1 = fmaxf(M1, 0.f);
    float M2 = fv + sgx;
    if (p > 0) M2 = fmaxf(M2, 0.f);
    lm[(b * LSEQ + p) * 6 + c] = fmaxf(M1, M2);
}

// ---------------- hop fold: [f1,phi1] / [g1,gam1] per token (U from global/L2) ----------------
__global__ __launch_bounds__(64) void hopfold_kernel(const float* __restrict__ xc2,
        const float* __restrict__ U, const float* __restrict__ lm0,
        const float* __restrict__ f0, const float* __restrict__ g0,
        const float* __restrict__ bc,
        float* __restrict__ outF, float* __restrict__ outG) {
    int m = blockIdx.x;
    int y = blockIdx.y;
    int tid = threadIdx.x;
    const float* Urows = U + (y ? 256 : 0) * 12;
    float p[12];
    #pragma unroll
    for (int c = 0; c < 12; ++c) p[c] = 0.f;
    for (int k = tid; k < 256; k += 64) {
        float a = xc2[m * 256 + k];
        const float* ur = Urows + k * 12;
        #pragma unroll
        for (int c = 0; c < 12; ++c) p[c] += a * ur[c];
    }
    #pragma unroll
    for (int c = 0; c < 12; ++c)
        for (int off = 32; off >= 1; off >>= 1) p[c] += __shfl_xor(p[c], off, 64);
    if (tid == 0) {
        const float* Bb = U + (y ? 518 : 512) * 12;
        const float* Db = U + 524 * 12;
        const float* fg = y ? g0 : f0;
        float* out = y ? outG : outF;
        float lmv[6], fgv[6];
        #pragma unroll
        for (int j = 0; j < 6; ++j) { lmv[j] = lm0[m * 6 + j]; fgv[j] = fg[m * 6 + j]; }
        #pragma unroll
        for (int c = 0; c < 12; ++c) {
            float s = p[c];
            #pragma unroll
            for (int j = 0; j < 6; ++j) s += lmv[j] * Bb[j * 12 + c] + fgv[j] * Db[j * 12 + c];
            if (!y) { s += U[530 * 12 + c]; if (c < 6) s += bc[c]; }
            out[m * 12 + c] = s;
        }
    }
}

// ---------------- f2/g2 finalize ----------------
__global__ __launch_bounds__(128) void f2g2_kernel(const float* __restrict__ f1phi,
        const float* __restrict__ g1gam, const float* __restrict__ lm1,
        const float* __restrict__ U, const float* __restrict__ bc,
        float* __restrict__ f2, float* __restrict__ g2) {
    __shared__ float Us[19 * 12], bcs[6];
    int tid = threadIdx.x;
    for (int i = tid; i < 19 * 12; i += 128) Us[i] = U[512 * 12 + i];
    if (tid < 6) bcs[tid] = bc[tid];
    __syncthreads();
    int m = blockIdx.x * 128 + tid;
    float lmv[6], f1v[6], g1v[6];
    #pragma unroll
    for (int j = 0; j < 6; ++j) {
        lmv[j] = lm1[m * 6 + j];
        f1v[j] = f1phi[m * 12 + j];
        g1v[j] = g1gam[m * 12 + j];
    }
    #pragma unroll
    for (int c = 0; c < 6; ++c) {
        float sf = f1phi[m * 12 + 6 + c] + Us[18 * 12 + c] + bcs[c];
        float sg = g1gam[m * 12 + 6 + c];
        #pragma unroll
        for (int j = 0; j < 6; ++j) {
            sf += lmv[j] * Us[j * 12 + c]       + f1v[j] * Us[(12 + j) * 12 + c];
            sg += lmv[j] * Us[(6 + j) * 12 + c] + g1v[j] * Us[(12 + j) * 12 + c];
        }
        f2[m * 6 + c] = sf;
        g2[m * 6 + c] = sg;
    }
}

// ---------------- final separable write ----------------
__global__ __launch_bounds__(256) void writeout_kernel(const float* __restrict__ f2,
        const float* __restrict__ g2, float* __restrict__ out) {
    int idx = blockIdx.x * 256 + threadIdx.x;   // < 8*128*128*6
    int c = idx % 6;
    int r = idx / 6;
    int j = r & 127;
    int bi = r >> 7;
    int b = bi >> 7;
    out[idx] = f2[bi * 6 + c] + g2[(b * LSEQ + j) * 6 + c];
}

extern "C" void kernel_launch(void* const* d_in, const int* in_sizes, int n_in,
                              void* d_out, int out_size, void* d_ws, size_t ws_size,
                              hipStream_t stream) {
    const int*   x     = (const int*)d_in[0];
    const float* xmask = (const float*)d_in[2];
    const float* gen   = (const float*)d_in[3];
    const float* dom   = (const float*)d_in[4];
    const float* w1    = (const float*)d_in[5];
    const float* b1    = (const float*)d_in[6];
    const float* w2    = (const float*)d_in[7];
    const float* b2    = (const float*)d_in[8];
    const float* w3    = (const float*)d_in[9];
    const float* b3    = (const float*)d_in[10];
    const float* w4    = (const float*)d_in[11];
    const float* b4    = (const float*)d_in[12];
    const float* w5    = (const float*)d_in[13];
    const float* b5    = (const float*)d_in[14];
    const float* wq    = (const float*)d_in[15];
    const float* bq    = (const float*)d_in[16];
    const float* wv    = (const float*)d_in[17];
    const float* bv    = (const float*)d_in[18];
    const float* vv    = (const float*)d_in[19];
    const float* wf    = (const float*)d_in[20];
    const float* bf    = (const float*)d_in[21];
    const float* wc    = (const float*)d_in[22];
    const float* bc    = (const float*)d_in[23];

    float* ws = (float*)d_ws;
    float* emb   = ws;                  // 409600
    float* bufA  = emb   + 409600;      // 262144
    float* bufB  = bufA  + 262144;      // 262144
    float* xc2   = bufB  + 262144;      // 262144
    float* qb    = xc2   + 262144;      // 51200
    float* vb    = qb    + 51200;       // 51200
    float* w1T   = vb    + 51200;       // 256000
    float* w2T   = w1T   + 256000;      // 153600
    float* w3T   = w2T   + 153600;      // 327680
    float* w4T   = w3T   + 327680;      // 327680
    float* w5T   = w4T   + 327680;      // 327680
    float* Wfc   = w5T   + 327680;      // 3072
    float* U     = Wfc   + 3072;        // 6372
    float* f0    = U     + 6372;        // 6144
    float* g0    = f0    + 6144;
    float* lm0   = g0    + 6144;
    float* lm1   = lm0   + 6144;
    float* f1phi = lm1   + 6144;        // 12288
    float* g1gam = f1phi + 12288;       // 12288
    float* f2    = g1gam + 12288;       // 6144
    float* g2    = f2    + 6144;

    // --- staging: transposes + embedding + Wfc, one launch ---
    PreArgs pa;
    pa.src[0] = w1;  pa.dst[0] = w1T; pa.OC[0] = 128; pa.CI[0] = 400; pa.K[0] = 5;
    pa.src[1] = w2;  pa.dst[1] = w2T; pa.OC[1] = 128; pa.CI[1] = 400; pa.K[1] = 3;
    pa.src[2] = w3;  pa.dst[2] = w3T; pa.OC[2] = 256; pa.CI[2] = 256; pa.K[2] = 5;
    pa.src[3] = w4;  pa.dst[3] = w4T; pa.OC[3] = 256; pa.CI[3] = 256; pa.K[3] = 5;
    pa.src[4] = w5;  pa.dst[4] = w5T; pa.OC[4] = 256; pa.CI[4] = 256; pa.K[4] = 5;
    pa.x = x; pa.gen4 = (const float4*)gen; pa.dom4 = (const float4*)dom;
    pa.emb4 = (float4*)emb;
    pa.wf = wf; pa.wc = wc; pa.Wfc = Wfc;
    stage_kernel<<<dim3(1280, 7), 256, 0, stream>>>(pa);

    // --- conv1 (+U precompute on y==8) ---
    conv1_v2<<<dim3(64, 9), 256, 0, stream>>>(emb, w1T, b1, w2T, b2, bufA,
                                              wf, bf, wc, Wfc, U);
    conv256_v2<<<dim3(64, 8), 256, 0, stream>>>(bufA, w3T, b3, bufB);
    conv256_v2<<<dim3(64, 8), 256, 0, stream>>>(bufB, w4T, b4, bufA);
    conv256_v2<<<dim3(64, 8), 256, 0, stream>>>(bufA, w5T, b5, bufB);
    // xc = bufB

    // --- attention (+ fused f0/g0) ---
    qv_v2<<<M_TOK, 128, 0, stream>>>(bufB, wq, bq, wv, bv, qb, vb);
    attn_v2<<<M_TOK, 256, 0, stream>>>(bufB, qb, vb, vv, xmask, wc, bc, xc2, f0, g0);

    // --- hops (fully folded, wide grids) ---
    lm_scan_v3<<<48, 128, 0, stream>>>(f0, g0, 6, lm0);
    hopfold_kernel<<<dim3(M_TOK, 2), 64, 0, stream>>>(xc2, U, lm0, f0, g0, bc, f1phi, g1gam);
    lm_scan_v3<<<48, 128, 0, stream>>>(f1phi, g1gam, 12, lm1);
    f2g2_kernel<<<8, 128, 0, stream>>>(f1phi, g1gam, lm1, U, bc, f2, g2);

    // --- out[b,i,j,c] = f2[b,i,c] + g2[b,j,c] ---
    writeout_kernel<<<(BB*LSEQ*LSEQ*6)/256, 256, 0, stream>>>(f2, g2, (float*)d_out);
}

// Round 8
// 241.020 us; speedup vs baseline: 1.2392x; 1.0863x over previous
//
#include <hip/hip_runtime.h>
#include <math.h>

#define LSEQ 128
#define BB 8
#define M_TOK (BB*LSEQ)   // 1024

typedef __attribute__((ext_vector_type(8))) short short8;
typedef __attribute__((ext_vector_type(4))) float floatx4;

__device__ __forceinline__ unsigned short bf16_rne(float v) {
    union { float f; unsigned u; } a; a.f = v;
    return (unsigned short)((a.u + 0x7fffu + ((a.u >> 16) & 1u)) >> 16);
}
__device__ __forceinline__ float bf16_to_f(unsigned short h) {
    union { unsigned u; float f; } b; b.u = ((unsigned)h) << 16;
    return b.f;
}
__device__ __forceinline__ void split2(float v, unsigned short& h, unsigned short& l) {
    h = bf16_rne(v);
    l = bf16_rne(v - bf16_to_f(h));
}

// ---------------- staging: pack all conv weights (split bf16, MFMA B-layout),
// embedding gather+split, Wfc — one launch ----------------
// B-layout (conv256): dst linear idx = ((kk*32+cg)*256 + oc)*8 + j, ci = cg*8+j
// B-layout (conv1):   dst linear idx = ((kk*52+cg)*OC  + oc)*8 + j, ci = cg*8+j (pad ci>=400 -> 0)
struct PreArgs {
    const float *w1, *w2, *w3, *w4, *w5;
    unsigned short *B1h, *B1l, *B2h, *B2l, *B3h, *B3l, *B4h, *B4l, *B5h, *B5l;
    const int* x;
    const float* gen;
    const float* dom;
    unsigned short *Eh, *El;
    const float* wf;
    const float* wc;
    float* Wfc;
};
__global__ __launch_bounds__(256) void stage_kernel(PreArgs a) {
    int y = blockIdx.y;
    int tid = threadIdx.x;
    if (y < 3) {
        // conv256 weights
        const float* w = (y == 0) ? a.w3 : (y == 1) ? a.w4 : a.w5;
        unsigned short* dh = (y == 0) ? a.B3h : (y == 1) ? a.B4h : a.B5h;
        unsigned short* dl = (y == 0) ? a.B3l : (y == 1) ? a.B4l : a.B5l;
        int idx = blockIdx.x * 256 + tid;          // < 327680 exactly
        int j = idx & 7;
        int n = (idx >> 3) & 255;
        int g = idx >> 11;
        int cg = g & 31, kk = g >> 5;
        int ci = cg * 8 + j;
        float v = w[(n * 256 + ci) * 5 + kk];
        unsigned short h, l; split2(v, h, l);
        dh[idx] = h; dl[idx] = l;
    } else if (y == 3) {
        // w1: OC=128, CG=52 (ci padded to 416), K=5
        int idx = blockIdx.x * 256 + tid;
        if (idx >= 5 * 52 * 128 * 8) return;
        int j = idx & 7;
        int n = (idx >> 3) & 127;
        int g = idx >> 10;
        int cg = g % 52, kk = g / 52;
        int ci = cg * 8 + j;
        float v = (ci < 400) ? a.w1[(n * 400 + ci) * 5 + kk] : 0.f;
        unsigned short h, l; split2(v, h, l);
        a.B1h[idx] = h; a.B1l[idx] = l;
    } else if (y == 4) {
        // w2: OC=128, CG=52, K=3
        int idx = blockIdx.x * 256 + tid;
        if (idx >= 3 * 52 * 128 * 8) return;
        int j = idx & 7;
        int n = (idx >> 3) & 127;
        int g = idx >> 10;
        int cg = g % 52, kk = g / 52;
        int ci = cg * 8 + j;
        float v = (ci < 400) ? a.w2[(n * 400 + ci) * 3 + kk] : 0.f;
        unsigned short h, l; split2(v, h, l);
        a.B2h[idx] = h; a.B2l[idx] = l;
    } else if (y == 5) {
        // embedding gather + split, rows padded to 416
        int m = blockIdx.x;
        if (m >= M_TOK) return;
        int t = a.x[m];
        for (int c = tid; c < 416; c += 256) {
            float v = (c < 300) ? a.gen[t * 300 + c]
                    : (c < 400) ? a.dom[t * 100 + (c - 300)] : 0.f;
            unsigned short h, l; split2(v, h, l);
            a.Eh[m * 416 + c] = h;
            a.El[m * 416 + c] = l;
        }
    } else {
        // Wfc[r,c] = sum_n wf[r,n]*wc[n,c], r < 512
        int r = blockIdx.x;
        if (r >= 512 || tid >= 64) return;
        int l = tid;
        float p[6] = {0,0,0,0,0,0};
        const float* row = a.wf + r * 512;
        #pragma unroll
        for (int k = 0; k < 8; ++k) {
            int n = l + 64 * k;
            float v = row[n];
            #pragma unroll
            for (int c = 0; c < 6; ++c) p[c] += v * a.wc[n * 6 + c];
        }
        #pragma unroll
        for (int c = 0; c < 6; ++c)
            for (int off = 32; off >= 1; off >>= 1) p[c] += __shfl_xor(p[c], off, 64);
        if (l == 0) {
            #pragma unroll
            for (int c = 0; c < 6; ++c) a.Wfc[r * 6 + c] = p[c];
        }
    }
}

// ---------------- conv1 MFMA (+precomp2 on by==4): 400ch(pad416) -> 128(k5)++128(k3), relu, split-bf16 out ----------------
__global__ __launch_bounds__(256) void conv1_mfma(
        const unsigned short* __restrict__ Eh, const unsigned short* __restrict__ El,
        const unsigned short* __restrict__ B1h, const unsigned short* __restrict__ B1l,
        const unsigned short* __restrict__ B2h, const unsigned short* __restrict__ B2l,
        const float* __restrict__ b1, const float* __restrict__ b2,
        unsigned short* __restrict__ Xoh, unsigned short* __restrict__ Xol,
        const float* __restrict__ wf, const float* __restrict__ bf,
        const float* __restrict__ wc, const float* __restrict__ Wfc,
        float* __restrict__ U) {
    __shared__ __align__(16) unsigned short xsh[20 * 424];
    __shared__ __align__(16) unsigned short xsl[20 * 424];
    int by = blockIdx.y;
    int tid = threadIdx.x;
    if (by == 4) {
        // precomp2: U[r,0:12] = row_r @ [wc | Wfc]
        if (tid >= 64) return;
        int l = tid;
        for (int i = 0; i < 9; ++i) {
            int r = blockIdx.x + 64 * i;
            if (r >= 531) break;
            const float* row = (r < 530) ? (wf + r * 512) : bf;
            float p[12];
            #pragma unroll
            for (int c = 0; c < 12; ++c) p[c] = 0.f;
            #pragma unroll
            for (int k = 0; k < 8; ++k) {
                int n = l + 64 * k;
                float v = row[n];
                #pragma unroll
                for (int c = 0; c < 6; ++c) {
                    p[c]     += v * wc[n * 6 + c];
                    p[c + 6] += v * Wfc[n * 6 + c];
                }
            }
            #pragma unroll
            for (int c = 0; c < 12; ++c)
                for (int off = 32; off >= 1; off >>= 1) p[c] += __shfl_xor(p[c], off, 64);
            if (l == 0) {
                #pragma unroll
                for (int c = 0; c < 12; ++c) U[r * 12 + c] = p[c];
            }
        }
        return;
    }
    int mt = blockIdx.x;
    int p0 = mt * 16;
    int b = p0 >> 7, l0 = p0 & 127;
    // stage 20 rows x 416 ci (hi+lo), zero-padded at batch edges
    for (int i = tid; i < 2 * 1040; i += 256) {
        int sel = i >= 1040;
        int u2 = sel ? i - 1040 : i;
        int j = u2 / 52, cg = u2 % 52;
        int l = l0 - 2 + j;
        short8 v = {0,0,0,0,0,0,0,0};
        if (l >= 0 && l < 128) {
            const unsigned short* src = (sel ? El : Eh) + (b * 128 + l) * 416 + cg * 8;
            v = *(const short8*)src;
        }
        *(short8*)((sel ? xsl : xsh) + j * 424 + cg * 8) = v;
    }
    __syncthreads();
    int w = tid >> 6, lane = tid & 63;
    int m = lane & 15, q = lane >> 4;
    bool br2 = (by >= 2);
    int n0b = (by & 1) * 64;
    int nB = n0b + w * 16 + m;           // lane&15 doubles as n for B and m for A
    floatx4 acc0 = {0,0,0,0}, acc1 = {0,0,0,0}, acc2 = {0,0,0,0};
    if (!br2) {
        for (int kk = 0; kk < 5; ++kk) {
            const unsigned short* arh = xsh + (m + kk) * 424;
            const unsigned short* arl = xsl + (m + kk) * 424;
            #pragma unroll
            for (int u = 0; u < 13; ++u) {
                short8 ah = *(const short8*)(arh + u * 32 + q * 8);
                short8 al = *(const short8*)(arl + u * 32 + q * 8);
                int boff = (((kk * 52 + u * 4 + q) * 128) + nB) * 8;
                short8 bh = *(const short8*)(B1h + boff);
                short8 bl = *(const short8*)(B1l + boff);
                acc0 = __builtin_amdgcn_mfma_f32_16x16x32_bf16(ah, bh, acc0, 0, 0, 0);
                acc1 = __builtin_amdgcn_mfma_f32_16x16x32_bf16(ah, bl, acc1, 0, 0, 0);
                acc2 = __builtin_amdgcn_mfma_f32_16x16x32_bf16(al, bh, acc2, 0, 0, 0);
            }
        }
    } else {
        for (int kk = 0; kk < 3; ++kk) {
            const unsigned short* arh = xsh + (m + kk + 1) * 424;
            const unsigned short* arl = xsl + (m + kk + 1) * 424;
            #pragma unroll
            for (int u = 0; u < 13; ++u) {
                short8 ah = *(const short8*)(arh + u * 32 + q * 8);
                short8 al = *(const short8*)(arl + u * 32 + q * 8);
                int boff = (((kk * 52 + u * 4 + q) * 128) + nB) * 8;
                short8 bh = *(const short8*)(B2h + boff);
                short8 bl = *(const short8*)(B2l + boff);
                acc0 = __builtin_amdgcn_mfma_f32_16x16x32_bf16(ah, bh, acc0, 0, 0, 0);
                acc1 = __builtin_amdgcn_mfma_f32_16x16x32_bf16(ah, bl, acc1, 0, 0, 0);
                acc2 = __builtin_amdgcn_mfma_f32_16x16x32_bf16(al, bh, acc2, 0, 0, 0);
            }
        }
    }
    __syncthreads();
    float* fl = (float*)xsh;   // 16 x 68 tile
    #pragma unroll
    for (int reg = 0; reg < 4; ++reg)
        fl[(q * 4 + reg) * 68 + w * 16 + m] = acc0[reg] + acc1[reg] + acc2[reg];
    __syncthreads();
    int ocb = br2 ? 128 + n0b : n0b;
    const float* bias = br2 ? b2 : b1;
    #pragma unroll
    for (int i = 0; i < 4; ++i) {
        int e = tid + 256 * i;
        int mm = e >> 6, nn = e & 63;
        float val = fl[mm * 68 + nn] + bias[n0b + nn];
        val = fmaxf(val, 0.f);
        unsigned short h, l; split2(val, h, l);
        int o = (p0 + mm) * 256 + ocb + nn;
        Xoh[o] = h; Xol[o] = l;
    }
}

// ---------------- conv256 MFMA: 256->256, k=5, p=2, relu; outmode 0=split bf16, 1=fp32 ----------------
__global__ __launch_bounds__(256) void conv256_mfma(
        const unsigned short* __restrict__ Xih, const unsigned short* __restrict__ Xil,
        const unsigned short* __restrict__ Bh, const unsigned short* __restrict__ Bl,
        const float* __restrict__ bias, int outmode,
        unsigned short* __restrict__ Xoh, unsigned short* __restrict__ Xol,
        float* __restrict__ fout) {
    __shared__ __align__(16) unsigned short xsh[20 * 264];
    __shared__ __align__(16) unsigned short xsl[20 * 264];
    int mt = blockIdx.x;
    int p0 = mt * 16;
    int b = p0 >> 7, l0 = p0 & 127;
    int n0 = blockIdx.y * 64;
    int tid = threadIdx.x;
    for (int i = tid; i < 2 * 640; i += 256) {
        int sel = i >= 640;
        int u2 = sel ? i - 640 : i;
        int j = u2 >> 5, cg = u2 & 31;
        int l = l0 - 2 + j;
        short8 v = {0,0,0,0,0,0,0,0};
        if (l >= 0 && l < 128) {
            const unsigned short* src = (sel ? Xil : Xih) + (b * 128 + l) * 256 + cg * 8;
            v = *(const short8*)src;
        }
        *(short8*)((sel ? xsl : xsh) + j * 264 + cg * 8) = v;
    }
    __syncthreads();
    int w = tid >> 6, lane = tid & 63;
    int m = lane & 15, q = lane >> 4;
    int nB = n0 + w * 16 + m;
    floatx4 acc0 = {0,0,0,0}, acc1 = {0,0,0,0}, acc2 = {0,0,0,0};
    for (int kk = 0; kk < 5; ++kk) {
        const unsigned short* arh = xsh + (m + kk) * 264;
        const unsigned short* arl = xsl + (m + kk) * 264;
        #pragma unroll
        for (int u = 0; u < 8; ++u) {
            short8 ah = *(const short8*)(arh + u * 32 + q * 8);
            short8 al = *(const short8*)(arl + u * 32 + q * 8);
            int boff = (((kk * 32 + u * 4 + q) * 256) + nB) * 8;
            short8 bh = *(const short8*)(Bh + boff);
            short8 bl = *(const short8*)(Bl + boff);
            acc0 = __builtin_amdgcn_mfma_f32_16x16x32_bf16(ah, bh, acc0, 0, 0, 0);
        acc1 = __builtin_amdgcn_mfma_f32_16x16x32_bf16(ah, bl, acc1, 0, 0, 0);
            acc2 = __builtin_amdgcn_mfma_f32_16x16x32_bf16(al, bh, acc2, 0, 0, 0);
        }
    }
    __syncthreads();
    float* fl = (float*)xsh;   // 16 x 68 tile
    #pragma unroll
    for (int reg = 0; reg < 4; ++reg)
        fl[(q * 4 + reg) * 68 + w * 16 + m] = acc0[reg] + acc1[reg] + acc2[reg];
    __syncthreads();
    #pragma unroll
    for (int i = 0; i < 4; ++i) {
        int e = tid + 256 * i;
        int mm = e >> 6, nn = e & 63;
        float val = fl[mm * 68 + nn] + bias[n0 + nn];
        val = fmaxf(val, 0.f);
        int o = (p0 + mm) * 256 + n0 + nn;
        if (outmode == 0) {
            unsigned short h, l; split2(val, h, l);
            Xoh[o] = h; Xol[o] = l;
        } else {
            fout[o] = val;
        }
    }
}

// ---------------- q/v projection: 2 waves per block (wave0=q, wave1=v) ----------------
__global__ __launch_bounds__(128) void qv_v2(const float* __restrict__ xc,
        const float* __restrict__ wq, const float* __restrict__ bq,
        const float* __restrict__ wv, const float* __restrict__ bv,
        float* __restrict__ q, float* __restrict__ v) {
    int m = blockIdx.x;
    int tid = threadIdx.x;
    int w = tid >> 6, d = tid & 63;
    if (d >= 50) return;
    const float* W = w ? wv : wq;
    float a = w ? bv[d] : bq[d];
    const float* xm = xc + m * 256;
    #pragma unroll 8
    for (int c = 0; c < 256; ++c) a += xm[c] * W[c * 50 + d];
    (w ? v : q)[m * 50 + d] = a;
}

// ---------------- attention v2: 256 threads/row, LDS-staged V, fast tanh ----------------
__global__ __launch_bounds__(256) void attn_v2(const float* __restrict__ xc,
        const float* __restrict__ q, const float* __restrict__ v,
        const float* __restrict__ vv, const float* __restrict__ xmask,
        const float* __restrict__ wc, const float* __restrict__ bc,
        float* __restrict__ xc2, float* __restrict__ f0, float* __restrict__ g0) {
    __shared__ float vs[128 * 50];   // 25.6 KB
    __shared__ float spart[128], aarr[128], xrow[256], qrow[52], vvs[52], red[4];
    int bi = blockIdx.x;             // b*L + i
    int b = bi >> 7;
    int tid = threadIdx.x;
    for (int idx = tid; idx < 128 * 50; idx += 256) vs[idx] = v[b * 6400 + idx];
    if (tid < 50) { qrow[tid] = q[bi * 50 + tid]; vvs[tid] = vv[tid]; }
    __syncthreads();
    int j = tid & 127, half = tid >> 7;
    int d0 = half * 25;
    const float* vj = vs + j * 50 + d0;
    float s = 0.f;
    #pragma unroll
    for (int d = 0; d < 25; ++d) {
        float x = qrow[d0 + d] + vj[d];
        float e = __expf(2.f * x);               // tanh(x) = 1 - 2/(e^(2x)+1)
        s += (1.f - 2.f / (e + 1.f)) * vvs[d0 + d];
    }
    if (half) spart[j] = s;
    __syncthreads();
    float stot = 0.f;
    if (!half) {
        stot = s + spart[j];
        if (xmask[b * LSEQ + j] == 0.f) stot = -1e9f;
    }
    if (tid < 128) {
        float m = stot;
        #pragma unroll
        for (int off = 32; off >= 1; off >>= 1) m = fmaxf(m, __shfl_xor(m, off, 64));
        if ((tid & 63) == 0) red[tid >> 6] = m;
    }
    __syncthreads();
    float mx = fmaxf(red[0], red[1]);
    float e = 0.f;
    if (tid < 128) {
        e = __expf(stot - mx);
        float su = e;
        #pragma unroll
        for (int off = 32; off >= 1; off >>= 1) su += __shfl_xor(su, off, 64);
        if ((tid & 63) == 0) red[2 + (tid >> 6)] = su;
    }
    __syncthreads();
    float denom = red[2] + red[3];
    if (tid < 128) aarr[j] = e / denom;
    __syncthreads();
    float maskI = xmask[bi];
    const float* xcb = xc + b * LSEQ * 256;
    float acc = 0.f;
    #pragma unroll 8
    for (int jj = 0; jj < 128; ++jj) acc += aarr[jj] * xcb[jj * 256 + tid];
    float val = xc[bi * 256 + tid] + acc * maskI;
    xc2[bi * 256 + tid] = val;
    xrow[tid] = val;
    __syncthreads();
    int grp = tid >> 4, l16 = tid & 15;
    if (grp < 12) {
        int c = grp % 6, gsel = grp / 6;
        const float* wcc = wc + gsel * 256 * 6 + c;
        float a = 0.f;
        #pragma unroll
        for (int ch = l16; ch < 256; ch += 16) a += xrow[ch] * wcc[ch * 6];
        #pragma unroll
        for (int off = 8; off >= 1; off >>= 1) a += __shfl_down(a, off, 16);
        if (l16 == 0) {
            if (gsel == 0) f0[bi * 6 + c] = a + bc[c];
            else           g0[bi * 6 + c] = a;
        }
    }
}

// ---------------- lm scan (strided input): parallel prefix/suffix max ----------------
__global__ __launch_bounds__(128) void lm_scan_v3(const float* __restrict__ f,
        const float* __restrict__ g, int stride, float* __restrict__ lm) {
    __shared__ float sf[128], sg[128];
    int bc = blockIdx.x;          // b*6 + c
    int b = bc / 6, c = bc - b * 6;
    int p = threadIdx.x;
    float fv = f[(b * LSEQ + p) * stride + c];
    float gv = g[(b * LSEQ + p) * stride + c];
    sf[p] = fv; sg[p] = gv;
    __syncthreads();
    float pf = fv, sgx = gv;
    #pragma unroll
    for (int off = 1; off < 128; off <<= 1) {
        float a = (p >= off) ? sf[p - off] : -INFINITY;
        float d = (p + off < 128) ? sg[p + off] : -INFINITY;
        __syncthreads();
        pf = fmaxf(pf, a); sgx = fmaxf(sgx, d);
        sf[p] = pf; sg[p] = sgx;
        __syncthreads();
    }
    float M1 = pf + gv;
    if (p < LSEQ - 1) M1 = fmaxf(M1, 0.f);
    float M2 = fv + sgx;
    if (p > 0) M2 = fmaxf(M2, 0.f);
    lm[(b * LSEQ + p) * 6 + c] = fmaxf(M1, M2);
}

// ---------------- hop fold: [f1,phi1] / [g1,gam1] per token (U from global/L2) ----------------
__global__ __launch_bounds__(64) void hopfold_kernel(const float* __restrict__ xc2,
        const float* __restrict__ U, const float* __restrict__ lm0,
        const float* __restrict__ f0, const float* __restrict__ g0,
        const float* __restrict__ bc,
        float* __restrict__ outF, float* __restrict__ outG) {
    int m = blockIdx.x;
    int y = blockIdx.y;
    int tid = threadIdx.x;
    const float* Urows = U + (y ? 256 : 0) * 12;
    float p[12];
    #pragma unroll
    for (int c = 0; c < 12; ++c) p[c] = 0.f;
    for (int k = tid; k < 256; k += 64) {
        float a = xc2[m * 256 + k];
        const float* ur = Urows + k * 12;
        #pragma unroll
        for (int c = 0; c < 12; ++c) p[c] += a * ur[c];
    }
    #pragma unroll
    for (int c = 0; c < 12; ++c)
        for (int off = 32; off >= 1; off >>= 1) p[c] += __shfl_xor(p[c], off, 64);
    if (tid == 0) {
        const float* Bb = U + (y ? 518 : 512) * 12;
        const float* Db = U + 524 * 12;
        const float* fg = y ? g0 : f0;
        float* out = y ? outG : outF;
        float lmv[6], fgv[6];
        #pragma unroll
        for (int j = 0; j < 6; ++j) { lmv[j] = lm0[m * 6 + j]; fgv[j] = fg[m * 6 + j]; }
        #pragma unroll
        for (int c = 0; c < 12; ++c) {
            float s = p[c];
            #pragma unroll
            for (int j = 0; j < 6; ++j) s += lmv[j] * Bb[j * 12 + c] + fgv[j] * Db[j * 12 + c];
            if (!y) { s += U[530 * 12 + c]; if (c < 6) s += bc[c]; }
            out[m * 12 + c] = s;
        }
    }
}

// ---------------- f2/g2 finalize ----------------
__global__ __launch_bounds__(128) void f2g2_kernel(const float* __restrict__ f1phi,
        const float* __restrict__ g1gam, const float* __restrict__ lm1,
        const float* __restrict__ U, const float* __restrict__ bc,
        float* __restrict__ f2, float* __restrict__ g2) {
    __shared__ float Us[19 * 12], bcs[6];
    int tid = threadIdx.x;
    for (int i = tid; i < 19 * 12; i += 128) Us[i] = U[512 * 12 + i];
    if (tid < 6) bcs[tid] = bc[tid];
    __syncthreads();
    int m = blockIdx.x * 128 + tid;
    float lmv[6], f1v[6], g1v[6];
    #pragma unroll
    for (int j = 0; j < 6; ++j) {
        lmv[j] = lm1[m * 6 + j];
        f1v[j] = f1phi[m * 12 + j];
        g1v[j] = g1gam[m * 12 + j];
    }
    #pragma unroll
    for (int c = 0; c < 6; ++c) {
        float sf = f1phi[m * 12 + 6 + c] + Us[18 * 12 + c] + bcs[c];
        float sg = g1gam[m * 12 + 6 + c];
        #pragma unroll
        for (int j = 0; j < 6; ++j) {
            sf += lmv[j] * Us[j * 12 + c]       + f1v[j] * Us[(12 + j) * 12 + c];
            sg += lmv[j] * Us[(6 + j) * 12 + c] + g1v[j] * Us[(12 + j) * 12 + c];
        }
        f2[m * 6 + c] = sf;
        g2[m * 6 + c] = sg;
    }
}

// ---------------- final separable write ----------------
__global__ __launch_bounds__(256) void writeout_kernel(const float* __restrict__ f2,
        const float* __restrict__ g2, float* __restrict__ out) {
    int idx = blockIdx.x * 256 + threadIdx.x;   // < 8*128*128*6
    int c = idx % 6;
    int r = idx / 6;
    int j = r & 127;
    int bi = r >> 7;
    int b = bi >> 7;
    out[idx] = f2[bi * 6 + c] + g2[(b * LSEQ + j) * 6 + c];
}

extern "C" void kernel_launch(void* const* d_in, const int* in_sizes, int n_in,
                              void* d_out, int out_size, void* d_ws, size_t ws_size,
                              hipStream_t stream) {
    const int*   x     = (const int*)d_in[0];
    const float* xmask = (const float*)d_in[2];
    const float* gen   = (const float*)d_in[3];
    const float* dom   = (const float*)d_in[4];
    const float* w1    = (const float*)d_in[5];
    const float* b1    = (const float*)d_in[6];
    const float* w2    = (const float*)d_in[7];
    const float* b2    = (const float*)d_in[8];
    const float* w3    = (const float*)d_in[9];
    const float* b3    = (const float*)d_in[10];
    const float* w4    = (const float*)d_in[11];
    const float* b4    = (const float*)d_in[12];
    const float* w5    = (const float*)d_in[13];
    const float* b5    = (const float*)d_in[14];
    const float* wq    = (const float*)d_in[15];
    const float* bq    = (const float*)d_in[16];
    const float* wv    = (const float*)d_in[17];
    const float* bv    = (const float*)d_in[18];
    const float* vv    = (const float*)d_in[19];
    const float* wf    = (const float*)d_in[20];
    const float* bf    = (const float*)d_in[21];
    const float* wc    = (const float*)d_in[22];
    const float* bc    = (const float*)d_in[23];

    // fp32 region
    float* fb = (float*)d_ws;
    float* bufB  = fb;                   // 262144  (xc, conv5 out)
    float* xc2   = bufB  + 262144;       // 262144
    float* qb    = xc2   + 262144;       // 51200
    float* vb    = qb    + 51200;        // 51200
    float* Wfc   = vb    + 51200;        // 3072
    float* U     = Wfc   + 3072;         // 6376 (pad)
    float* f0    = U     + 6376;         // 6144
    float* g0    = f0    + 6144;
    float* lm0   = g0    + 6144;
    float* lm1   = lm0   + 6144;
    float* f1phi = lm1   + 6144;         // 12288
    float* g1gam = f1phi + 12288;        // 12288
    float* f2    = g1gam + 12288;        // 6144
    float* g2    = f2    + 6144;
    // bf16 (ushort) region, 16B aligned
    unsigned short* sb = (unsigned short*)(g2 + 6144 + 32);
    unsigned short* Eh  = sb;             sb += 425984;  // 1024*416
    unsigned short* El  = sb;             sb += 425984;
    unsigned short* B1h = sb;             sb += 266240;  // 5*52*128*8
    unsigned short* B1l = sb;             sb += 266240;
    unsigned short* B2h = sb;             sb += 159744;  // 3*52*128*8
    unsigned short* B2l = sb;             sb += 159744;
    unsigned short* B3h = sb;             sb += 327680;  // 5*32*256*8
    unsigned short* B3l = sb;             sb += 327680;
    unsigned short* B4h = sb;             sb += 327680;
    unsigned short* B4l = sb;             sb += 327680;
    unsigned short* B5h = sb;             sb += 327680;
    unsigned short* B5l = sb;             sb += 327680;
    unsigned short* X3h = sb;             sb += 262144;  // 1024*256
    unsigned short* X3l = sb;             sb += 262144;
    unsigned short* X4h = sb;             sb += 262144;
    unsigned short* X4l = sb;             sb += 262144;

    // --- staging: weight packs (split bf16) + embedding + Wfc ---
    PreArgs pa;
    pa.w1 = w1; pa.w2 = w2; pa.w3 = w3; pa.w4 = w4; pa.w5 = w5;
    pa.B1h = B1h; pa.B1l = B1l; pa.B2h = B2h; pa.B2l = B2l;
    pa.B3h = B3h; pa.B3l = B3l; pa.B4h = B4h; pa.B4l = B4l;
    pa.B5h = B5h; pa.B5l = B5l;
    pa.x = x; pa.gen = gen; pa.dom = dom; pa.Eh = Eh; pa.El = El;
    pa.wf = wf; pa.wc = wc; pa.Wfc = Wfc;
    stage_kernel<<<dim3(1280, 7), 256, 0, stream>>>(pa);

    // --- convs (MFMA split-bf16) ---
    conv1_mfma<<<dim3(64, 5), 256, 0, stream>>>(Eh, El, B1h, B1l, B2h, B2l, b1, b2,
                                                X3h, X3l, wf, bf, wc, Wfc, U);
    conv256_mfma<<<dim3(64, 4), 256, 0, stream>>>(X3h, X3l, B3h, B3l, b3, 0,
                                                  X4h, X4l, nullptr);
    conv256_mfma<<<dim3(64, 4), 256, 0, stream>>>(X4h, X4l, B4h, B4l, b4, 0,
                                                  X3h, X3l, nullptr);
    conv256_mfma<<<dim3(64, 4), 256, 0, stream>>>(X3h, X3l, B5h, B5l, b5, 1,
                                                  nullptr, nullptr, bufB);
    // xc = bufB (fp32)

    // --- attention (+ fused f0/g0) ---
    qv_v2<<<M_TOK, 128, 0, stream>>>(bufB, wq, bq, wv, bv, qb, vb);
    attn_v2<<<M_TOK, 256, 0, stream>>>(bufB, qb, vb, vv, xmask, wc, bc, xc2, f0, g0);

    // --- hops (fully folded, wide grids) ---
    lm_scan_v3<<<48, 128, 0, stream>>>(f0, g0, 6, lm0);
    hopfold_kernel<<<dim3(M_TOK, 2), 64, 0, stream>>>(xc2, U, lm0, f0, g0, bc, f1phi, g1gam);
    lm_scan_v3<<<48, 128, 0, stream>>>(f1phi, g1gam, 12, lm1);
    f2g2_kernel<<<8, 128, 0, stream>>>(f1phi, g1gam, lm1, U, bc, f2, g2);

    // --- out[b,i,j,c] = f2[b,i,c] + g2[b,j,c] ---
    writeout_kernel<<<(BB*LSEQ*LSEQ*6)/256, 256, 0, stream>>>(f2, g2, (float*)d_out);
}